// Round 6
// baseline (320.759 us; speedup 1.0000x reference)
//
#include <hip/hip_runtime.h>
#include <hip/hip_bf16.h>

// Problem constants
#define NB 4
#define NT 256
#define NU 100
#define NH 512      // H_ENC = H_DEC = 512
#define NI 512      // INNER
#define NV 1024     // VOCAB
#define MROWS (NB * NT * NU)   // 102400 joint rows

typedef __attribute__((ext_vector_type(4))) float f32x4;
typedef __attribute__((ext_vector_type(8))) __bf16 bf16x8;

// round-to-nearest-even f32 -> bf16 bits
static __device__ __forceinline__ unsigned int f2bf(float f) {
  unsigned int u = __float_as_uint(f);
  return (u + 0x7FFFu + ((u >> 16) & 1u)) >> 16;
}

// tanh(x) = 1 - 2/(1+e^{2x})
static __device__ __forceinline__ float fast_tanh(float x) {
  float e = __expf(2.f * x);
  return 1.f - 2.f * __builtin_amdgcn_rcpf(1.f + e);
}

// async global->LDS, 16B per lane
static __device__ __forceinline__ void gload16(const void* g, void* l) {
  __builtin_amdgcn_global_load_lds(
      (const __attribute__((address_space(1))) unsigned int*)(g),
      (__attribute__((address_space(3))) unsigned int*)(l), 16, 0, 0);
}

// ---------------------------------------------------------------------------
// Merged projections: pe[r][i] = enc[r][:] . W1[i][0:512]   (r < 1024)
//                     pd[r][i] = dec[r][:] . W1[i][512:1024] (r < 400)
// ---------------------------------------------------------------------------
__global__ __launch_bounds__(256) void proj_kernel(
    const float* __restrict__ enc, const float* __restrict__ dec,
    const float* __restrict__ W1, float* __restrict__ pe, float* __restrict__ pd) {
  __shared__ float As[64][17];
  __shared__ float Bs[64][17];
  const int bx = blockIdx.x;
  const float* A;
  float* P;
  int Mrows, colOff, row0;
  if (bx < 16) { A = enc; P = pe; Mrows = NB * NT; colOff = 0;  row0 = bx * 64; }
  else         { A = dec; P = pd; Mrows = NB * NU; colOff = NH; row0 = (bx - 16) * 64; }
  const int col0 = blockIdx.y * 64;
  const int tx = threadIdx.x;
  const int tr = tx >> 4, tc = tx & 15;
  const int lr = tx >> 2, lc = (tx & 3) * 4;
  float acc[4][4] = {};
  for (int k0 = 0; k0 < NH; k0 += 16) {
    float4 av = make_float4(0.f, 0.f, 0.f, 0.f);
    if (row0 + lr < Mrows)
      av = *(const float4*)(A + (size_t)(row0 + lr) * NH + k0 + lc);
    float4 bv = *(const float4*)(W1 + (size_t)(col0 + lr) * (NH + NH) + colOff + k0 + lc);
    As[lr][lc] = av.x; As[lr][lc + 1] = av.y; As[lr][lc + 2] = av.z; As[lr][lc + 3] = av.w;
    Bs[lr][lc] = bv.x; Bs[lr][lc + 1] = bv.y; Bs[lr][lc + 2] = bv.z; Bs[lr][lc + 3] = bv.w;
    __syncthreads();
#pragma unroll
    for (int kk = 0; kk < 16; ++kk) {
      float a4[4], b4[4];
#pragma unroll
      for (int i = 0; i < 4; ++i) { a4[i] = As[tr * 4 + i][kk]; b4[i] = Bs[tc * 4 + i][kk]; }
#pragma unroll
      for (int i = 0; i < 4; ++i)
#pragma unroll
        for (int j = 0; j < 4; ++j) acc[i][j] = fmaf(a4[i], b4[j], acc[i][j]);
    }
    __syncthreads();
  }
#pragma unroll
  for (int i = 0; i < 4; ++i) {
    int r = row0 + tr * 4 + i;
    if (r < Mrows) {
#pragma unroll
      for (int j = 0; j < 4; ++j)
        P[(size_t)r * NI + col0 + tc * 4 + j] = acc[i][j];
    }
  }
}

// ---------------------------------------------------------------------------
// W2 f32 -> bf16 bits (1024x512), 4 per thread
// ---------------------------------------------------------------------------
__global__ __launch_bounds__(256) void cvt_w2_kernel(const float* __restrict__ W2,
                                                     unsigned short* __restrict__ w2b) {
  int i = (blockIdx.x * 256 + threadIdx.x) * 4;
  float4 v = *(const float4*)(W2 + i);
  uint2 o;
  o.x = f2bf(v.x) | (f2bf(v.y) << 16);
  o.y = f2bf(v.z) | (f2bf(v.w) << 16);
  *(uint2*)(w2b + i) = o;
}

// ---------------------------------------------------------------------------
// Fused joint: block = 128 joint rows x 512 vocab cols (half of NV).
// Phase 0: A-panel hid[128][512] = tanh(pe+pd+b1) -> bf16 into ldsA ONCE
//          (128 KB, XOR-swizzled granules). pe/pd are 2.8 MB -> L2-resident;
//          A never touches HBM.
// Main:    g = 0..31 (4 vocab panels x 8 k-tiles of BK=64). B (W2 panel tile,
//          16 KB) double-buffered via global_load_lds width-16 with inverse-
//          swizzled source; STAGE(g+1) issued BEFORE the 32 MFMAs of g so the
//          barrier's vmcnt drain is covered by compute. W2 = 1 MB, L2-resident.
// 4 waves (2x2), wave tile 64x64. LDS = 128K + 32K = 160 KB -> 1 block/CU.
// Output stores are non-temporal (419 MB stream; keep L2 for pe/pd/W2).
// ---------------------------------------------------------------------------
__global__ __launch_bounds__(256) void fused_joint_kernel(
    const float* __restrict__ pe, const float* __restrict__ pd,
    const float* __restrict__ b1, const unsigned short* __restrict__ w2b,
    const float* __restrict__ b2, float* __restrict__ out) {
  __shared__ unsigned char ldsA[131072];    // 128 rows x 512 k bf16, swizzled
  __shared__ unsigned char ldsB[32768];     // 2 x (128 cols x 64 k bf16)
  const int tx = threadIdx.x;
  const int mt = blockIdx.x >> 1;           // 0..799
  const int nh = blockIdx.x & 1;            // vocab half
  const int R0 = mt * 128;
  const int CB = nh * 512;

  // stage B tile g=0 (panel 0, kt=0); latency hides under phase 0
#define STAGEB(G, BUF) do {                                                   \
    const int p_ = (G) >> 3, kt_ = (G) & 7;                                   \
    unsigned char* dB_ = ldsB + (BUF) * 16384;                                \
    _Pragma("unroll")                                                         \
    for (int q = 0; q < 4; ++q) {                                             \
      int c = q * 256 + tx;                 /* 16B chunk 0..1023 */           \
      int cl = c >> 3;                      /* local col 0..127 */            \
      int sl = (c & 7) ^ (cl & 7);          /* logical k-slot */              \
      gload16(w2b + (size_t)(CB + p_ * 128 + cl) * NI + kt_ * 64 + sl * 8,    \
              dB_ + c * 16);                                                  \
    }                                                                         \
  } while (0)

  STAGEB(0, 0);

  // Phase 0: hid panel -> ldsA (32 passes x 256 threads x 8 elems)
#pragma unroll 2
  for (int pass = 0; pass < 32; ++pass) {
    int idx = pass * 256 + tx;
    int row = idx >> 6;                     // 0..127
    int i0 = (idx & 63) * 8;
    int g = R0 + row;
    int b = g / (NT * NU);
    int rem = g - b * (NT * NU);
    int t = rem / NU;
    int u = rem - t * NU;
    const float* peP = pe + (size_t)(b * NT + t) * NI + i0;
    const float* pdP = pd + (size_t)(b * NU + u) * NI + i0;
    float4 p0 = *(const float4*)peP, p1 = *(const float4*)(peP + 4);
    float4 q0 = *(const float4*)pdP, q1 = *(const float4*)(pdP + 4);
    float4 c0 = *(const float4*)(b1 + i0), c1 = *(const float4*)(b1 + i0 + 4);
    uint4 pk;
    pk.x = f2bf(fast_tanh(p0.x + q0.x + c0.x)) | (f2bf(fast_tanh(p0.y + q0.y + c0.y)) << 16);
    pk.y = f2bf(fast_tanh(p0.z + q0.z + c0.z)) | (f2bf(fast_tanh(p0.w + q0.w + c0.w)) << 16);
    pk.z = f2bf(fast_tanh(p1.x + q1.x + c1.x)) | (f2bf(fast_tanh(p1.y + q1.y + c1.y)) << 16);
    pk.w = f2bf(fast_tanh(p1.z + q1.z + c1.z)) | (f2bf(fast_tanh(p1.w + q1.w + c1.w)) << 16);
    int gi = i0 >> 3;                       // granule 0..63
    int bo = row * 1024 + ((gi ^ (row & 7)) << 4);
    *(uint4*)(ldsA + bo) = pk;
  }
  __syncthreads();   // drains phase-0 ds_writes AND B tile-0 loads

  const int lane = tx & 63, wid = tx >> 6;
  const int wr = wid >> 1, wc = wid & 1;    // 2x2 wave grid; wave tile 64x64
  const int lr = lane & 15, lq = lane >> 4;

  f32x4 acc[4][4];
#pragma unroll
  for (int mf = 0; mf < 4; ++mf)
#pragma unroll
    for (int nf = 0; nf < 4; ++nf)
#pragma unroll
      for (int z = 0; z < 4; ++z) acc[mf][nf][z] = 0.f;

  for (int g = 0; g < 32; ++g) {
    const int cur = g & 1;
    if (g < 31) STAGEB(g + 1, cur ^ 1);     // in flight during MFMA below
    const int p = g >> 3, kt = g & 7;
    const unsigned char* bufB = ldsB + cur * 16384;
#pragma unroll
    for (int kh = 0; kh < 2; ++kh) {
      bf16x8 af[4], bfv[4];
#pragma unroll
      for (int nf = 0; nf < 4; ++nf) {
        int cl = wc * 64 + nf * 16 + lr;
        int sb = (kh * 4 + lq) ^ (cl & 7);
        bfv[nf] = *(const bf16x8*)(bufB + cl * 128 + (sb << 4));
      }
#pragma unroll
      for (int mf = 0; mf < 4; ++mf) {
        int row = wr * 64 + mf * 16 + lr;
        int gi = kt * 8 + kh * 4 + lq;      // granule in full-K row
        af[mf] = *(const bf16x8*)(ldsA + row * 1024 + ((gi ^ (row & 7)) << 4));
      }
      __builtin_amdgcn_s_setprio(1);
#pragma unroll
      for (int mf = 0; mf < 4; ++mf)
#pragma unroll
        for (int nf = 0; nf < 4; ++nf)
          acc[mf][nf] = __builtin_amdgcn_mfma_f32_16x16x32_bf16(
              af[mf], bfv[nf], acc[mf][nf], 0, 0, 0);
      __builtin_amdgcn_s_setprio(0);
    }

    if (kt == 7) {
      // epilogue for vocab panel p: + b2, non-temporal fp32 stores
#pragma unroll
      for (int nf = 0; nf < 4; ++nf) {
        int col = CB + p * 128 + wc * 64 + nf * 16 + lr;
        float bb = b2[col];
#pragma unroll
        for (int mf = 0; mf < 4; ++mf) {
#pragma unroll
          for (int j = 0; j < 4; ++j) {
            int grow = R0 + wr * 64 + mf * 16 + lq * 4 + j;
            __builtin_nontemporal_store(acc[mf][nf][j] + bb,
                                        &out[(size_t)grow * NV + col]);
          }
        }
      }
#pragma unroll
      for (int mf = 0; mf < 4; ++mf)
#pragma unroll
        for (int nf = 0; nf < 4; ++nf)
#pragma unroll
          for (int z = 0; z < 4; ++z) acc[mf][nf][z] = 0.f;
    }
    if (g < 31) __syncthreads();            // vmcnt drain covered by compute
  }
#undef STAGEB
}

extern "C" void kernel_launch(void* const* d_in, const int* in_sizes, int n_in,
                              void* d_out, int out_size, void* d_ws, size_t ws_size,
                              hipStream_t stream) {
  const float* enc = (const float*)d_in[0];
  const float* dec = (const float*)d_in[1];
  const float* W1  = (const float*)d_in[2];
  const float* b1  = (const float*)d_in[3];
  const float* W2  = (const float*)d_in[4];
  const float* b2  = (const float*)d_in[5];
  float* out = (float*)d_out;
  char* ws = (char*)d_ws;

  float* pe = (float*)ws;                                   // 2 MB
  float* pd = (float*)(ws + (2u << 20));                    // 0.8 MB
  unsigned short* w2b = (unsigned short*)(ws + (3u << 20)); // 1 MB

  proj_kernel<<<dim3(23, 8), 256, 0, stream>>>(enc, dec, W1, pe, pd);
  cvt_w2_kernel<<<512, 256, 0, stream>>>(W2, w2b);
  fused_joint_kernel<<<(MROWS / 128) * 2, 256, 0, stream>>>(pe, pd, b1, w2b, b2, out);
}

// Round 7
// 284.140 us; speedup vs baseline: 1.1289x; 1.1289x over previous
//
#include <hip/hip_runtime.h>
#include <hip/hip_bf16.h>

// Problem constants
#define NB 4
#define NT 256
#define NU 100
#define NH 512      // H_ENC = H_DEC = 512
#define NI 512      // INNER
#define NV 1024     // VOCAB
#define MROWS (NB * NT * NU)   // 102400 joint rows

typedef __attribute__((ext_vector_type(4))) float f32x4;
typedef __attribute__((ext_vector_type(8))) __bf16 bf16x8;

// round-to-nearest-even f32 -> bf16 bits
static __device__ __forceinline__ unsigned int f2bf(float f) {
  unsigned int u = __float_as_uint(f);
  return (u + 0x7FFFu + ((u >> 16) & 1u)) >> 16;
}

// tanh(x) = 1 - 2/(1+e^{2x})
static __device__ __forceinline__ float fast_tanh(float x) {
  float e = __expf(2.f * x);
  return 1.f - 2.f * __builtin_amdgcn_rcpf(1.f + e);
}

// async global->LDS, 16B per lane
static __device__ __forceinline__ void gload16(const void* g, void* l) {
  __builtin_amdgcn_global_load_lds(
      (const __attribute__((address_space(1))) unsigned int*)(g),
      (__attribute__((address_space(3))) unsigned int*)(l), 16, 0, 0);
}

// ---------------------------------------------------------------------------
// Merged projections: pe[r][i] = enc[r][:] . W1[i][0:512]   (r < 1024)
//                     pd[r][i] = dec[r][:] . W1[i][512:1024] (r < 400)
// ---------------------------------------------------------------------------
__global__ __launch_bounds__(256) void proj_kernel(
    const float* __restrict__ enc, const float* __restrict__ dec,
    const float* __restrict__ W1, float* __restrict__ pe, float* __restrict__ pd) {
  __shared__ float As[64][17];
  __shared__ float Bs[64][17];
  const int bx = blockIdx.x;
  const float* A;
  float* P;
  int Mrows, colOff, row0;
  if (bx < 16) { A = enc; P = pe; Mrows = NB * NT; colOff = 0;  row0 = bx * 64; }
  else         { A = dec; P = pd; Mrows = NB * NU; colOff = NH; row0 = (bx - 16) * 64; }
  const int col0 = blockIdx.y * 64;
  const int tx = threadIdx.x;
  const int tr = tx >> 4, tc = tx & 15;
  const int lr = tx >> 2, lc = (tx & 3) * 4;
  float acc[4][4] = {};
  for (int k0 = 0; k0 < NH; k0 += 16) {
    float4 av = make_float4(0.f, 0.f, 0.f, 0.f);
    if (row0 + lr < Mrows)
      av = *(const float4*)(A + (size_t)(row0 + lr) * NH + k0 + lc);
    float4 bv = *(const float4*)(W1 + (size_t)(col0 + lr) * (NH + NH) + colOff + k0 + lc);
    As[lr][lc] = av.x; As[lr][lc + 1] = av.y; As[lr][lc + 2] = av.z; As[lr][lc + 3] = av.w;
    Bs[lr][lc] = bv.x; Bs[lr][lc + 1] = bv.y; Bs[lr][lc + 2] = bv.z; Bs[lr][lc + 3] = bv.w;
    __syncthreads();
#pragma unroll
    for (int kk = 0; kk < 16; ++kk) {
      float a4[4], b4[4];
#pragma unroll
      for (int i = 0; i < 4; ++i) { a4[i] = As[tr * 4 + i][kk]; b4[i] = Bs[tc * 4 + i][kk]; }
#pragma unroll
      for (int i = 0; i < 4; ++i)
#pragma unroll
        for (int j = 0; j < 4; ++j) acc[i][j] = fmaf(a4[i], b4[j], acc[i][j]);
    }
    __syncthreads();
  }
#pragma unroll
  for (int i = 0; i < 4; ++i) {
    int r = row0 + tr * 4 + i;
    if (r < Mrows) {
#pragma unroll
      for (int j = 0; j < 4; ++j)
        P[(size_t)r * NI + col0 + tc * 4 + j] = acc[i][j];
    }
  }
}

// ---------------------------------------------------------------------------
// W2 f32 -> bf16 bits (1024x512), 4 per thread
// ---------------------------------------------------------------------------
__global__ __launch_bounds__(256) void cvt_w2_kernel(const float* __restrict__ W2,
                                                     unsigned short* __restrict__ w2b) {
  int i = (blockIdx.x * 256 + threadIdx.x) * 4;
  float4 v = *(const float4*)(W2 + i);
  uint2 o;
  o.x = f2bf(v.x) | (f2bf(v.y) << 16);
  o.y = f2bf(v.z) | (f2bf(v.w) << 16);
  *(uint2*)(w2b + i) = o;
}

// ---------------------------------------------------------------------------
// Fused joint, counted-vmcnt ring pipeline.
// Block = 128 joint rows x FULL 1024 vocab (tanh computed exactly once).
// 512 threads / 8 waves (4M x 2N), wave tile 32 rows x 64 cols.
// LDS: A panel 128x512 bf16 = 128 KB (phase 0, XOR-swizzled) +
//      B ring 4 x 8 KB (BK=32, 128-col panel tiles) = 160 KB total.
// Per iter g (p = g>>4 vocab panel, kt = g&15 k-step):
//   s_waitcnt vmcnt(2)   -> my slot-g chunks landed (3 stages in flight max)
//   s_barrier            -> ALL waves' slot-g chunks visible; all waves done
//                           reading slot g-1 (lgkm'd before their MFMA(g-1))
//   ds_read af[2]/bfv[4] from slot g&3 + A panel
//   STAGEB(g+3) -> slot (g+3)&3 (== g-1's, now safe)
//   s_waitcnt lgkmcnt(0); sched_barrier(0)   [rule #18]
//   8x mfma_16x16x32_bf16 (setprio-wrapped)
// Epilogue per panel (kt==15): bias from preloaded VGPRs, regular stores,
// one vmcnt(0) drain at the natural boundary (stores never drained in-loop).
// ---------------------------------------------------------------------------
__global__ __launch_bounds__(512) void fused_joint_kernel(
    const float* __restrict__ pe, const float* __restrict__ pd,
    const float* __restrict__ b1, const unsigned short* __restrict__ w2b,
    const float* __restrict__ b2, float* __restrict__ out) {
  __shared__ unsigned char ldsA[131072];    // 128 rows x 512 k bf16, swizzled
  __shared__ unsigned char ldsB[32768];     // 4 slots x (128 cols x 32 k bf16)
  const int tx = threadIdx.x;
  const int R0 = blockIdx.x * 128;

  const int lane = tx & 63, wid = tx >> 6;
  const int wr = wid >> 1, wc = wid & 1;    // 4M x 2N; wave tile 32 x 64
  const int lr = lane & 15, lq = lane >> 4;

  // B stage: tile gg (p=gg>>4, kt=gg&15), 8KB, 1 x 16B chunk per thread.
  // LDS dest linear; source inverse-swizzled: phys chunk pc stores logical
  // granule pc ^ ((cl>>1)&3).
#define STAGEB(GG, SLOT) do {                                                 \
    int p_ = (GG) >> 4, kt_ = (GG) & 15;                                      \
    int cl_ = tx >> 2;                                                        \
    int lg_ = (tx & 3) ^ ((cl_ >> 1) & 3);                                    \
    gload16(w2b + (size_t)(p_ * 128 + cl_) * NI + kt_ * 32 + lg_ * 8,         \
            ldsB + (SLOT) * 8192 + tx * 16);                                  \
  } while (0)

  STAGEB(0, 0); STAGEB(1, 1); STAGEB(2, 2);   // overlap with phase 0

  // bias preload: the 32 b2 values this thread will add (8 panels x 4 nf)
  float bias[8][4];
#pragma unroll
  for (int p = 0; p < 8; ++p)
#pragma unroll
    for (int nf = 0; nf < 4; ++nf)
      bias[p][nf] = b2[p * 128 + wc * 64 + nf * 16 + lr];

  // Phase 0: A panel = tanh(pe+pd+b1) -> bf16, swizzled (16 passes x 512 thr)
#pragma unroll 2
  for (int pass = 0; pass < 16; ++pass) {
    int idx = pass * 512 + tx;              // 8192 granules of 8 elems
    int row = idx >> 6;                     // 0..127
    int i0 = (idx & 63) * 8;
    int g = R0 + row;
    int b = g / (NT * NU);
    int rem = g - b * (NT * NU);
    int t = rem / NU;
    int u = rem - t * NU;
    const float* peP = pe + (size_t)(b * NT + t) * NI + i0;
    const float* pdP = pd + (size_t)(b * NU + u) * NI + i0;
    float4 p0 = *(const float4*)peP, p1 = *(const float4*)(peP + 4);
    float4 q0 = *(const float4*)pdP, q1 = *(const float4*)(pdP + 4);
    float4 c0 = *(const float4*)(b1 + i0), c1 = *(const float4*)(b1 + i0 + 4);
    uint4 pk;
    pk.x = f2bf(fast_tanh(p0.x + q0.x + c0.x)) | (f2bf(fast_tanh(p0.y + q0.y + c0.y)) << 16);
    pk.y = f2bf(fast_tanh(p0.z + q0.z + c0.z)) | (f2bf(fast_tanh(p0.w + q0.w + c0.w)) << 16);
    pk.z = f2bf(fast_tanh(p1.x + q1.x + c1.x)) | (f2bf(fast_tanh(p1.y + q1.y + c1.y)) << 16);
    pk.w = f2bf(fast_tanh(p1.z + q1.z + c1.z)) | (f2bf(fast_tanh(p1.w + q1.w + c1.w)) << 16);
    int gi = idx & 63;                      // granule 0..63
    int bo = row * 1024 + ((gi ^ (row & 7)) << 4);
    *(uint4*)(ldsA + bo) = pk;
  }
  __syncthreads();     // drains phase-0 ds_writes + stages 0-2 + bias loads

  f32x4 acc[2][4];
#pragma unroll
  for (int mf = 0; mf < 2; ++mf)
#pragma unroll
    for (int nf = 0; nf < 4; ++nf)
#pragma unroll
      for (int z = 0; z < 4; ++z) acc[mf][nf][z] = 0.f;

#pragma unroll 4
  for (int g = 0; g < 128; ++g) {
    const int p = g >> 4, kt = g & 15, slot = g & 3;

    // my slot-g chunk landed (only stages for g+1,g+2 may remain in flight)
    asm volatile("s_waitcnt vmcnt(2)" ::: "memory");
    // -> after barrier: ALL waves' slot-g chunks visible; slot g-1 free
    __builtin_amdgcn_s_barrier();

    bf16x8 af[2], bfv[4];
#pragma unroll
    for (int nf = 0; nf < 4; ++nf) {
      int cl = wc * 64 + nf * 16 + lr;
      bfv[nf] = *(const bf16x8*)(ldsB + slot * 8192 + cl * 64 +
                                 ((lq ^ ((cl >> 1) & 3)) << 4));
    }
#pragma unroll
    for (int mf = 0; mf < 2; ++mf) {
      int row = wr * 32 + mf * 16 + lr;
      int gi = kt * 4 + lq;
      af[mf] = *(const bf16x8*)(ldsA + row * 1024 + ((gi ^ (row & 7)) << 4));
    }

    if (g + 3 < 128) STAGEB(g + 3, (g + 3) & 3);

    asm volatile("s_waitcnt lgkmcnt(0)" ::: "memory");
    __builtin_amdgcn_sched_barrier(0);

    __builtin_amdgcn_s_setprio(1);
#pragma unroll
    for (int mf = 0; mf < 2; ++mf)
#pragma unroll
      for (int nf = 0; nf < 4; ++nf)
        acc[mf][nf] = __builtin_amdgcn_mfma_f32_16x16x32_bf16(
            af[mf], bfv[nf], acc[mf][nf], 0, 0, 0);
    __builtin_amdgcn_s_setprio(0);

    if (kt == 15) {
      // epilogue for vocab panel p: regular fp32 stores (L2 assembles lines)
#pragma unroll
      for (int nf = 0; nf < 4; ++nf) {
        int col = p * 128 + wc * 64 + nf * 16 + lr;
#pragma unroll
        for (int mf = 0; mf < 2; ++mf) {
#pragma unroll
          for (int j = 0; j < 4; ++j) {
            int grow = R0 + wr * 32 + mf * 16 + lq * 4 + j;
            out[(size_t)grow * NV + col] = acc[mf][nf][j] + bias[p][nf];
          }
        }
      }
#pragma unroll
      for (int mf = 0; mf < 2; ++mf)
#pragma unroll
        for (int nf = 0; nf < 4; ++nf)
#pragma unroll
          for (int z = 0; z < 4; ++z) acc[mf][nf][z] = 0.f;
      // drain stores (and in-flight stages) once per panel, at the boundary
      asm volatile("s_waitcnt vmcnt(0)" ::: "memory");
    }
  }
#undef STAGEB
}

extern "C" void kernel_launch(void* const* d_in, const int* in_sizes, int n_in,
                              void* d_out, int out_size, void* d_ws, size_t ws_size,
                              hipStream_t stream) {
  const float* enc = (const float*)d_in[0];
  const float* dec = (const float*)d_in[1];
  const float* W1  = (const float*)d_in[2];
  const float* b1  = (const float*)d_in[3];
  const float* W2  = (const float*)d_in[4];
  const float* b2  = (const float*)d_in[5];
  float* out = (float*)d_out;
  char* ws = (char*)d_ws;

  float* pe = (float*)ws;                                   // 2 MB
  float* pd = (float*)(ws + (2u << 20));                    // 0.8 MB
  unsigned short* w2b = (unsigned short*)(ws + (3u << 20)); // 1 MB

  proj_kernel<<<dim3(23, 8), 256, 0, stream>>>(enc, dec, W1, pe, pd);
  cvt_w2_kernel<<<512, 256, 0, stream>>>(W2, w2b);
  fused_joint_kernel<<<MROWS / 128, 512, 0, stream>>>(pe, pd, b1, w2b, b2, out);
}